// Round 1
// baseline (487.158 us; speedup 1.0000x reference)
//
#include <hip/hip_runtime.h>
#include <cstddef>

#define NC 16
#define HID 128
#define IMH 256
#define IMW 256
#define NB 32
#define TILE 16
#define HR 18    // halo region = TILE+2 (pixels needing the MLP)
#define XS 20    // staged X region = TILE+4 (sobel halo of HR)
#define NTHREADS 384
#define WROW 36  // packed weight row: [b1 | w1eff[18] | w2T[16] | pad]

// Collapse w1's 48 columns into 18 effective feature columns.
// Feature groups (torch grouped-conv layout, out ch o uses in ch o//3):
//  f0..f4  : ident(X[0..4])  cols {3f..3f+2}
//  f5      : ident(X[5])     col  {15}
//  f6      : sx(X[5])        cols {16,17}
//  f7..f10 : sx(X[6..9])     cols {18..29} (3 each)
//  f11     : sx(X[10])       cols {30,31}
//  f12     : sy(X[10])       col  {32}
//  f13..f17: sy(X[11..15])   cols {33..47} (3 each)
__global__ void prep_weights(const float* __restrict__ w1,
                             const float* __restrict__ b1,
                             const float* __restrict__ w2,
                             float* __restrict__ wpack) {
    int j = threadIdx.x;
    if (j >= HID) return;
    const int starts[18] = {0,3,6,9,12,15,16,18,21,24,27,30,32,33,36,39,42,45};
    const int lens[18]   = {3,3,3,3,3,1,2,3,3,3,3,2,1,3,3,3,3,3};
    float* row = wpack + j * WROW;
    row[0] = b1[j];
    #pragma unroll
    for (int f = 0; f < 18; ++f) {
        float s = 0.f;
        for (int k = 0; k < lens[f]; ++k) s += w1[j*48 + starts[f] + k];
        row[1+f] = s;
    }
    #pragma unroll
    for (int c = 0; c < NC; ++c) row[19+c] = w2[c*HID + j];
    row[35] = 0.f;
}

__global__ __launch_bounds__(NTHREADS)
void nca_fused(const float* __restrict__ X,
               const float* __restrict__ rand_u,
               const float* __restrict__ wpack,
               float* __restrict__ out) {
    __shared__ float sX[NC][XS][XS];  // staged X tile, zero-padded OOB
    __shared__ float sA[HR][HR];      // Xn alpha (post-update), 0 for OOB

    const int t  = threadIdx.x;
    const int x0 = blockIdx.x * TILE;
    const int y0 = blockIdx.y * TILE;
    const int b  = blockIdx.z;

    const float* Xb = X + (size_t)b * NC * IMH * IMW;

    // ---- stage X: 16 channels x 20x20, origin at tile-(-2,-2) ----
    for (int e = t; e < NC*XS*XS; e += NTHREADS) {
        int ch  = e / (XS*XS);
        int rem = e - ch*(XS*XS);
        int yy  = rem / XS;
        int xx  = rem - yy*XS;
        int gy = y0 + yy - 2, gx = x0 + xx - 2;
        float v = 0.f;
        if (gy >= 0 && gy < IMH && gx >= 0 && gx < IMW)
            v = Xb[(size_t)ch*IMH*IMW + (size_t)gy*IMW + gx];
        (&sX[0][0][0])[e] = v;
    }
    __syncthreads();

    // ---- per-pixel MLP at all 18x18 halo pixels (threads 0..323) ----
    float Xn[NC];
    #pragma unroll
    for (int c = 0; c < NC; ++c) Xn[c] = 0.f;
    bool interior = false;
    int hy = 0, hx = 0, gy = 0, gx = 0;

    if (t < HR*HR) {
        hy = t / HR; hx = t - hy*HR;
        gy = y0 + hy - 1; gx = x0 + hx - 1;
        const int sy = hy + 1, sxx = hx + 1;  // staged coords of this pixel

        float f[18];
        #pragma unroll
        for (int c = 0; c < 6; ++c) f[c] = sX[c][sy][sxx];
        #pragma unroll
        for (int i = 0; i < 6; ++i) {   // sobel_x on ch 5..10 -> f[6..11]
            const int ch = 5 + i;
            f[6+i] = ( -     sX[ch][sy-1][sxx-1] +     sX[ch][sy-1][sxx+1]
                       - 2.f*sX[ch][sy  ][sxx-1] + 2.f*sX[ch][sy  ][sxx+1]
                       -     sX[ch][sy+1][sxx-1] +     sX[ch][sy+1][sxx+1] ) * 0.125f;
        }
        #pragma unroll
        for (int i = 0; i < 6; ++i) {   // sobel_y on ch 10..15 -> f[12..17]
            const int ch = 10 + i;
            f[12+i] = ( -sX[ch][sy-1][sxx-1] - 2.f*sX[ch][sy-1][sxx] - sX[ch][sy-1][sxx+1]
                        +sX[ch][sy+1][sxx-1] + 2.f*sX[ch][sy+1][sxx] + sX[ch][sy+1][sxx+1] ) * 0.125f;
        }

        float acc[NC];
        #pragma unroll
        for (int c = 0; c < NC; ++c) acc[c] = 0.f;

        // 128 hidden units; weights at wave-uniform addresses -> s_load
        #pragma unroll 4
        for (int j = 0; j < HID; ++j) {
            const float* row = wpack + j*WROW;
            float hj = row[0];
            #pragma unroll
            for (int k = 0; k < 18; ++k) hj = fmaf(row[1+k], f[k], hj);
            hj = fmaxf(hj, 0.f);
            #pragma unroll
            for (int c = 0; c < NC; ++c) acc[c] = fmaf(row[19+c], hj, acc[c]);
        }

        const bool inb = (gy >= 0 && gy < IMH && gx >= 0 && gx < IMW);
        float m = 0.f;
        if (inb) m = (rand_u[(size_t)b*IMH*IMW + (size_t)gy*IMW + gx] < 0.5f) ? 1.f : 0.f;
        #pragma unroll
        for (int c = 0; c < NC; ++c) Xn[c] = sX[c][sy][sxx] + acc[c]*m;
        sA[hy][hx] = inb ? Xn[3] : 0.f;   // 0 acts as -inf for the >0.1 test
        interior = (hy >= 1 && hy <= TILE && hx >= 1 && hx <= TILE);
    }
    __syncthreads();

    // ---- masks + write (interior pixels only) ----
    if (interior) {
        float mpre  = sX[3][hy][hx];      // staged rows hy..hy+2 = sy-1..sy+1
        float mpost = sA[hy-1][hx-1];
        #pragma unroll
        for (int dy = 0; dy < 3; ++dy)
            #pragma unroll
            for (int dxx = 0; dxx < 3; ++dxx) {
                mpre  = fmaxf(mpre,  sX[3][hy+dy][hx+dxx]);
                mpost = fmaxf(mpost, sA[hy-1+dy][hx-1+dxx]);
            }
        const float live = (mpre > 0.1f && mpost > 0.1f) ? 1.f : 0.f;
        float* ob = out + (size_t)b*NC*IMH*IMW + (size_t)gy*IMW + gx;
        #pragma unroll
        for (int c = 0; c < NC; ++c) ob[(size_t)c*IMH*IMW] = Xn[c]*live;
    }
}

extern "C" void kernel_launch(void* const* d_in, const int* in_sizes, int n_in,
                              void* d_out, int out_size, void* d_ws, size_t ws_size,
                              hipStream_t stream) {
    const float* X  = (const float*)d_in[0];
    const float* w1 = (const float*)d_in[1];
    const float* b1 = (const float*)d_in[2];
    const float* w2 = (const float*)d_in[3];
    const float* ru = (const float*)d_in[4];
    float* out   = (float*)d_out;
    float* wpack = (float*)d_ws;   // 128*36*4 = 18432 bytes

    prep_weights<<<1, 128, 0, stream>>>(w1, b1, w2, wpack);

    dim3 grid(IMW/TILE, IMH/TILE, NB);
    nca_fused<<<grid, NTHREADS, 0, stream>>>(X, ru, wpack, out);
}